// Round 26
// baseline (1517.621 us; speedup 1.0000x reference)
//
#include <hip/hip_runtime.h>
#include <math.h>

#define B_ 1024
#define D_ 2048
#define H_ 2048
#define E_ 16
#define K_ 8
#define KEEP_ 6
#define EXP_ID_ 0

typedef double v4d __attribute__((ext_vector_type(4)));

// ---------------- ws layout ----------------
#define WS_OUTALL 0
#define WS_IDX    134217728
#define WS_VALS   (134217728 + 32768)
#define WS_ENERGY (134217728 + 65536)
#define WS_CNT    (134217728 + 98304)
#define WS_ROWS   (134217728 + 98560)      // E*B ints = 64 KB
#define WS_ROWTAB (134217728 + 164096)     // 256 ints
#define WS_COLTAB (134217728 + 165120)     // 256 ints
#define WS_OKFLG  (134217728 + 166144)     // 1 int (diagnostic)

// ---------------- 0. init: counters + probe flag ----------------
__global__ void init_cnt_kernel(int* __restrict__ cnt, int* __restrict__ okflg) {
  if (threadIdx.x < E_) cnt[threadIdx.x] = 0;
  if (threadIdx.x == 0) okflg[0] = 1;
}

// ---------------- 0b. MFMA f64 layout probe (1 wave) ----------------
// Input convention: lane l supplies A[l&15][l>>4], B[l>>4][l&15].
// Probe derives D's (lane,reg)->(row,col) mapping; validated composite (R18).
__global__ __launch_bounds__(64) void mfma_probe_kernel(
    int* __restrict__ rowtab, int* __restrict__ coltab, int* __restrict__ okflg) {
  const int l = threadIdx.x;
  const v4d z = {0.0, 0.0, 0.0, 0.0};
  double a1 = (double)(l & 15);
  double b1 = ((l >> 4) == 0) ? 1.0 : 0.0;
  v4d d1 = __builtin_amdgcn_mfma_f64_16x16x4f64(a1, b1, z, 0, 0, 0);
  double a2 = ((l >> 4) == 0) ? 1.0 : 0.0;
  double b2 = (double)(l & 15);
  v4d d2 = __builtin_amdgcn_mfma_f64_16x16x4f64(a2, b2, z, 0, 0, 0);
  double a3 = (double)((l & 15) + 1);
  double b3 = (double)((l & 15) + 1);
  v4d d3 = __builtin_amdgcn_mfma_f64_16x16x4f64(a3, b3, z, 0, 0, 0);

  int ok = 1;
#pragma unroll
  for (int g = 0; g < 4; ++g) {
    int r = (int)(d1[g] + 0.5);
    int c = (int)(d2[g] + 0.5);
    if (r < 0 || r > 15 || c < 0 || c > 15) { r = 0; c = 0; ok = 0; }
    rowtab[l * 4 + g] = r;
    coltab[l * 4 + g] = c;
    double expect = 4.0 * (double)(r + 1) * (double)(c + 1);
    if (d3[g] != expect) ok = 0;
  }
  if (!ok) okflg[0] = 0;
}

// ---------------- 1. gating: one wave per row, f64; emit row lists ----------
__global__ __launch_bounds__(64) void gate_kernel(
    const float* __restrict__ x, const float* __restrict__ Wg,
    const float* __restrict__ bg, int* __restrict__ idx, float* __restrict__ vals,
    int* __restrict__ cnt, int* __restrict__ rows) {
  const int b = blockIdx.x;
  const int lane = threadIdx.x;
  double acc[E_];
#pragma unroll
  for (int e = 0; e < E_; ++e) acc[e] = 0.0;
  for (int d = lane; d < D_; d += 64) {
    double xv = (double)x[(size_t)b * D_ + d];
    const float* w = Wg + (size_t)d * E_;
#pragma unroll
    for (int e = 0; e < E_; ++e) acc[e] = fma(xv, (double)w[e], acc[e]);
  }
  for (int off = 32; off > 0; off >>= 1) {
#pragma unroll
    for (int e = 0; e < E_; ++e) acc[e] += __shfl_down(acc[e], off, 64);
  }
  if (lane == 0) {
    double logit[E_];
#pragma unroll
    for (int e = 0; e < E_; ++e) logit[e] = acc[e] + (double)bg[e];
    double m = logit[0];
#pragma unroll
    for (int e = 1; e < E_; ++e) m = fmax(m, logit[e]);
    double p[E_], s = 0.0;
#pragma unroll
    for (int e = 0; e < E_; ++e) { p[e] = exp(logit[e] - m); s += p[e]; }
#pragma unroll
    for (int e = 0; e < E_; ++e) p[e] = p[e] / s;
    unsigned taken = 0;
    for (int j = 0; j < K_; ++j) {
      int best = -1; double bv = -1.0;
#pragma unroll
      for (int e = 0; e < E_; ++e)
        if (!((taken >> e) & 1u) && p[e] > bv) { bv = p[e]; best = e; }
      taken |= (1u << best);
      idx[b * K_ + j] = best;
      vals[b * K_ + j] = (float)bv;
    }
    taken |= 1u;   // rep expert always needed
#pragma unroll
    for (int e = 0; e < E_; ++e) {
      if ((taken >> e) & 1u) {
        int p2 = atomicAdd(&cnt[e], 1);
        rows[e * B_ + p2] = b;
      }
    }
  }
}

// ---- 2. GEMM: f64 MFMA; A from global (per-lane row, reg prefetch);
//      B in f32 LDS double-buffer BK=32; s_setprio(1) around MFMA cluster ----
// Global k-order per output identical to R22-R25 -> out_all bits identical.
#define BM 64
#define BN 64
#define BK 32

__global__ __launch_bounds__(256) void gemm_expert_kernel(
    const float* __restrict__ X, const float* __restrict__ We,
    const float* __restrict__ be, float* __restrict__ out_all,
    const int* __restrict__ cnt, const int* __restrict__ rows,
    const int* __restrict__ rowtab, const int* __restrict__ coltab) {
  const int e  = blockIdx.z;
  const int nrows = cnt[e];
  const int m0 = blockIdx.y * BM;
  if (m0 >= nrows) return;
  const int n0 = blockIdx.x * BN;
  const float* Bmat = We + (size_t)e * D_ * H_;
  const int* rl = rows + e * B_;

  __shared__ float Bs[2][BK][BN + 8];   // [2][32][72] f32 = 18432 B

  const int tid = threadIdx.x;
  const int brow  = tid >> 4;               // [0,16): stages rows brow, brow+16
  const int bcol4 = (tid & 15) * 4;         // {0..60}

  const float* bptr = Bmat + (size_t)brow * H_ + n0 + bcol4;

  const int lane = tid & 63;
  const int wave = tid >> 6;       // rows wave*16 .. +15
  const int lr = lane & 15;
  const int lq = lane >> 4;

  // lane's own A row (clamped; epilogue stores are guarded)
  const int aidx = m0 + wave * 16 + lr;
  const int agrow = rl[(aidx < nrows) ? aidx : (nrows - 1)];
  const float* arow = X + (size_t)agrow * D_;

  v4d acc[4];
#pragma unroll
  for (int c = 0; c < 4; ++c) acc[c] = (v4d){0.0, 0.0, 0.0, 0.0};

  // prologue: stage B tile 0 (k 0..31) into buf 0; A tile 0 into regs
  float4 bva = *(const float4*)(bptr);
  float4 bvb = *(const float4*)(bptr + (size_t)16 * H_);
  *(float4*)&Bs[0][brow][bcol4] = bva;
  *(float4*)&Bs[0][brow + 16][bcol4] = bvb;
  float a[8], na[8];
#pragma unroll
  for (int i = 0; i < 8; ++i) a[i] = arow[lq + 4 * i];

#define COMPUTE_TILE(BUF)                                                    \
  __builtin_amdgcn_s_setprio(1);                                             \
  _Pragma("unroll")                                                          \
  for (int i = 0; i < 8; ++i) {                                              \
    double a_ = (double)a[i];                                                \
    _Pragma("unroll")                                                        \
    for (int c = 0; c < 4; ++c)                                              \
      acc[c] = __builtin_amdgcn_mfma_f64_16x16x4f64(                         \
          a_, (double)Bs[BUF][4 * i + lq][c * 16 + lr], acc[c], 0, 0, 0);    \
  }                                                                          \
  __builtin_amdgcn_s_setprio(0);

  for (int k0 = 0; k0 < D_; k0 += 2 * BK) {
    // ---- phase 0: compute buf0 (k0..k0+31), prefetch k0+32, write buf1 ----
    __syncthreads();                       // buf0 writes visible; buf1 free
    bva = *(const float4*)(bptr + (size_t)(k0 + BK) * H_);
    bvb = *(const float4*)(bptr + (size_t)(k0 + BK + 16) * H_);
#pragma unroll
    for (int i = 0; i < 8; ++i) na[i] = arow[k0 + BK + lq + 4 * i];
    COMPUTE_TILE(0)
    *(float4*)&Bs[1][brow][bcol4] = bva;
    *(float4*)&Bs[1][brow + 16][bcol4] = bvb;
#pragma unroll
    for (int i = 0; i < 8; ++i) a[i] = na[i];
    // ---- phase 1: compute buf1 (k0+32..k0+63), prefetch k0+64, write buf0 ----
    __syncthreads();                       // buf1 writes visible; buf0 free
    const bool more = (k0 + 2 * BK) < D_;
    if (more) {
      bva = *(const float4*)(bptr + (size_t)(k0 + 2 * BK) * H_);
      bvb = *(const float4*)(bptr + (size_t)(k0 + 2 * BK + 16) * H_);
#pragma unroll
      for (int i = 0; i < 8; ++i) na[i] = arow[k0 + 2 * BK + lq + 4 * i];
    }
    COMPUTE_TILE(1)
    if (more) {
      *(float4*)&Bs[0][brow][bcol4] = bva;
      *(float4*)&Bs[0][brow + 16][bcol4] = bvb;
#pragma unroll
      for (int i = 0; i < 8; ++i) a[i] = na[i];
    }
  }
#undef COMPUTE_TILE

  // epilogue via probed D layout
  int drow[4], dcol[4];
#pragma unroll
  for (int g = 0; g < 4; ++g) {
    drow[g] = rowtab[lane * 4 + g];
    dcol[g] = coltab[lane * 4 + g];
  }
#pragma unroll
  for (int c = 0; c < 4; ++c) {
#pragma unroll
    for (int g = 0; g < 4; ++g) {
      const int rix = m0 + wave * 16 + drow[g];
      if (rix < nrows) {
        const int mrow = rl[rix];
        const int col = n0 + c * 16 + dcol[g];
        out_all[((size_t)mrow * E_ + e) * H_ + col] =
            (float)(acc[c][g] + (double)be[(size_t)e * H_ + col]);
      }
    }
  }
}

// ---- 3. energy: bit-replica of numpy f32 logsumexp (verified R11) ----
__global__ __launch_bounds__(256) void energy_kernel(
    const float* __restrict__ out_all, const int* __restrict__ idx,
    float* __restrict__ energy) {
  const int b = blockIdx.x, j = blockIdx.y, t = threadIdx.x;
  const int e = idx[b * K_ + j];
  if (e == EXP_ID_) {
    if (t == 0) energy[b * K_ + j] = 1.0f + (float)log(2048.0);
    return;
  }
  const float* rep = out_all + ((size_t)b * E_ + EXP_ID_) * H_;
  const float* ok  = out_all + ((size_t)b * E_ + e) * H_;

  __shared__ float cs[H_];
  __shared__ float red[256];
  __shared__ float chain[128];

  float mx = -2.0f;
  for (int h = t; h < H_; h += 256) {
    float r = rep[h], o = ok[h];
    float num = r * o;
    float den = fabsf(r) * fabsf(o) + 1e-8f;
    float c = num / den;
    cs[h] = c;
    mx = fmaxf(mx, c);
  }
  red[t] = mx;
  __syncthreads();
  for (int off = 128; off > 0; off >>= 1) {
    if (t < off) red[t] = fmaxf(red[t], red[t + off]);
    __syncthreads();
  }
  const float m = red[0];
  __syncthreads();

  if (t < 128) {
    const int blk = t >> 3, jj = t & 7;
    const float* base = cs + blk * 128;
    float d0 = base[jj] - m;
    float r = (float)exp((double)d0);
#pragma unroll
    for (int q = 1; q < 16; ++q) {
      float dq = base[q * 8 + jj] - m;
      float term = (float)exp((double)dq);
      r = r + term;
    }
    chain[t] = r;
  }
  __syncthreads();

  if (t == 0) {
    float Bsum[16];
#pragma unroll
    for (int blk = 0; blk < 16; ++blk) {
      const float* c8 = chain + blk * 8;
      float s01 = c8[0] + c8[1];
      float s23 = c8[2] + c8[3];
      float s45 = c8[4] + c8[5];
      float s67 = c8[6] + c8[7];
      Bsum[blk] = (s01 + s23) + (s45 + s67);
    }
    float C[8], D[4], Ee[2];
#pragma unroll
    for (int i = 0; i < 8; ++i) C[i] = Bsum[2 * i] + Bsum[2 * i + 1];
#pragma unroll
    for (int i = 0; i < 4; ++i) D[i] = C[2 * i] + C[2 * i + 1];
#pragma unroll
    for (int i = 0; i < 2; ++i) Ee[i] = D[2 * i] + D[2 * i + 1];
    float S = Ee[0] + Ee[1];
    energy[b * K_ + j] = m + (float)log((double)S);
  }
}

// ---- 4. select: stable rank on f32 E bits (exact ties -> lower j), keep 6 ----
__global__ __launch_bounds__(256) void final_kernel(
    const float* __restrict__ out_all, const int* __restrict__ idx,
    const float* __restrict__ vals, const float* __restrict__ energy,
    float* __restrict__ out) {
  const int b = blockIdx.x;
  const int h = blockIdx.y * 256 + threadIdx.x;
  float En[K_];
#pragma unroll
  for (int j = 0; j < K_; ++j) En[j] = energy[b * K_ + j];
  double s = 0.0;
#pragma unroll
  for (int j = 0; j < K_; ++j) {
    int pos = 0;
#pragma unroll
    for (int j2 = 0; j2 < K_; ++j2)
      pos += (En[j2] < En[j]) || (En[j2] == En[j] && j2 < j);
    if (pos < KEEP_) {
      int e = idx[b * K_ + j];
      s += (double)vals[b * K_ + j] *
           (double)out_all[((size_t)b * E_ + e) * H_ + h];
    }
  }
  out[(size_t)b * H_ + h] = (float)s;
}

// ---------------- launch ----------------
extern "C" void kernel_launch(void* const* d_in, const int* in_sizes, int n_in,
                              void* d_out, int out_size, void* d_ws, size_t ws_size,
                              hipStream_t stream) {
  const float* x  = (const float*)d_in[0];
  const float* Wg = (const float*)d_in[1];
  const float* bg = (const float*)d_in[2];
  const float* We = (const float*)d_in[3];
  const float* be = (const float*)d_in[4];
  float* out = (float*)d_out;

  char* ws = (char*)d_ws;
  float* out_all = (float*)(ws + WS_OUTALL);
  int*   idx     = (int*)(ws + WS_IDX);
  float* vals    = (float*)(ws + WS_VALS);
  float* energy  = (float*)(ws + WS_ENERGY);
  int*   cnt     = (int*)(ws + WS_CNT);
  int*   rows    = (int*)(ws + WS_ROWS);
  int*   rowtab  = (int*)(ws + WS_ROWTAB);
  int*   coltab  = (int*)(ws + WS_COLTAB);
  int*   okflg   = (int*)(ws + WS_OKFLG);

  init_cnt_kernel<<<dim3(1), dim3(64), 0, stream>>>(cnt, okflg);

  mfma_probe_kernel<<<dim3(1), dim3(64), 0, stream>>>(rowtab, coltab, okflg);

  gate_kernel<<<dim3(B_), dim3(64), 0, stream>>>(x, Wg, bg, idx, vals, cnt, rows);

  gemm_expert_kernel<<<dim3(H_ / BN, B_ / BM, E_), dim3(256), 0, stream>>>(
      x, We, be, out_all, cnt, rows, rowtab, coltab);

  energy_kernel<<<dim3(B_, K_), dim3(256), 0, stream>>>(out_all, idx, energy);

  final_kernel<<<dim3(B_, H_ / 256), dim3(256), 0, stream>>>(
      out_all, idx, vals, energy, out);
}

// Round 27
// 1468.633 us; speedup vs baseline: 1.0334x; 1.0334x over previous
//
#include <hip/hip_runtime.h>
#include <math.h>

#define B_ 1024
#define D_ 2048
#define H_ 2048
#define E_ 16
#define K_ 8
#define KEEP_ 6
#define EXP_ID_ 0

typedef double v4d __attribute__((ext_vector_type(4)));

// ---------------- ws layout ----------------
#define WS_OUTALL 0
#define WS_IDX    134217728
#define WS_VALS   (134217728 + 32768)
#define WS_ENERGY (134217728 + 65536)
#define WS_CNT    (134217728 + 98304)
#define WS_ROWS   (134217728 + 98560)      // E*B ints = 64 KB
#define WS_ROWTAB (134217728 + 164096)     // 256 ints
#define WS_COLTAB (134217728 + 165120)     // 256 ints
#define WS_OKFLG  (134217728 + 166144)     // 1 int (diagnostic)

// ---------------- 0. init: counters + probe flag ----------------
__global__ void init_cnt_kernel(int* __restrict__ cnt, int* __restrict__ okflg) {
  if (threadIdx.x < E_) cnt[threadIdx.x] = 0;
  if (threadIdx.x == 0) okflg[0] = 1;
}

// ---------------- 0b. MFMA f64 layout probe (1 wave) ----------------
// Input convention: lane l supplies A[l&15][l>>4], B[l>>4][l&15].
// Probe derives D's (lane,reg)->(row,col) mapping; validated composite (R18).
__global__ __launch_bounds__(64) void mfma_probe_kernel(
    int* __restrict__ rowtab, int* __restrict__ coltab, int* __restrict__ okflg) {
  const int l = threadIdx.x;
  const v4d z = {0.0, 0.0, 0.0, 0.0};
  double a1 = (double)(l & 15);
  double b1 = ((l >> 4) == 0) ? 1.0 : 0.0;
  v4d d1 = __builtin_amdgcn_mfma_f64_16x16x4f64(a1, b1, z, 0, 0, 0);
  double a2 = ((l >> 4) == 0) ? 1.0 : 0.0;
  double b2 = (double)(l & 15);
  v4d d2 = __builtin_amdgcn_mfma_f64_16x16x4f64(a2, b2, z, 0, 0, 0);
  double a3 = (double)((l & 15) + 1);
  double b3 = (double)((l & 15) + 1);
  v4d d3 = __builtin_amdgcn_mfma_f64_16x16x4f64(a3, b3, z, 0, 0, 0);

  int ok = 1;
#pragma unroll
  for (int g = 0; g < 4; ++g) {
    int r = (int)(d1[g] + 0.5);
    int c = (int)(d2[g] + 0.5);
    if (r < 0 || r > 15 || c < 0 || c > 15) { r = 0; c = 0; ok = 0; }
    rowtab[l * 4 + g] = r;
    coltab[l * 4 + g] = c;
    double expect = 4.0 * (double)(r + 1) * (double)(c + 1);
    if (d3[g] != expect) ok = 0;
  }
  if (!ok) okflg[0] = 0;
}

// ---------------- 1. gating: one wave per row, f64; emit row lists ----------
__global__ __launch_bounds__(64) void gate_kernel(
    const float* __restrict__ x, const float* __restrict__ Wg,
    const float* __restrict__ bg, int* __restrict__ idx, float* __restrict__ vals,
    int* __restrict__ cnt, int* __restrict__ rows) {
  const int b = blockIdx.x;
  const int lane = threadIdx.x;
  double acc[E_];
#pragma unroll
  for (int e = 0; e < E_; ++e) acc[e] = 0.0;
  for (int d = lane; d < D_; d += 64) {
    double xv = (double)x[(size_t)b * D_ + d];
    const float* w = Wg + (size_t)d * E_;
#pragma unroll
    for (int e = 0; e < E_; ++e) acc[e] = fma(xv, (double)w[e], acc[e]);
  }
  for (int off = 32; off > 0; off >>= 1) {
#pragma unroll
    for (int e = 0; e < E_; ++e) acc[e] += __shfl_down(acc[e], off, 64);
  }
  if (lane == 0) {
    double logit[E_];
#pragma unroll
    for (int e = 0; e < E_; ++e) logit[e] = acc[e] + (double)bg[e];
    double m = logit[0];
#pragma unroll
    for (int e = 1; e < E_; ++e) m = fmax(m, logit[e]);
    double p[E_], s = 0.0;
#pragma unroll
    for (int e = 0; e < E_; ++e) { p[e] = exp(logit[e] - m); s += p[e]; }
#pragma unroll
    for (int e = 0; e < E_; ++e) p[e] = p[e] / s;
    unsigned taken = 0;
    for (int j = 0; j < K_; ++j) {
      int best = -1; double bv = -1.0;
#pragma unroll
      for (int e = 0; e < E_; ++e)
        if (!((taken >> e) & 1u) && p[e] > bv) { bv = p[e]; best = e; }
      taken |= (1u << best);
      idx[b * K_ + j] = best;
      vals[b * K_ + j] = (float)bv;
    }
    taken |= 1u;   // rep expert always needed
#pragma unroll
    for (int e = 0; e < E_; ++e) {
      if ((taken >> e) & 1u) {
        int p2 = atomicAdd(&cnt[e], 1);
        rows[e * B_ + p2] = b;
      }
    }
  }
}

// ---- 2. GEMM: f64 MFMA, f32-in-LDS double-buffer, ONE barrier per K-step ----
// Bs pad +8 (stride 72 words): B-read bank = (8*lq+16c+lr)%32 -> exact 2-way (free).
// cvt_f64_f32 on read is exact; MFMA chain per output identical to R18-R26
// -> out_all bits identical.  (Best measured config: R23, 1468.9 us.)
#define BM 64
#define BN 64
#define BK 16

__global__ __launch_bounds__(256) void gemm_expert_kernel(
    const float* __restrict__ X, const float* __restrict__ We,
    const float* __restrict__ be, float* __restrict__ out_all,
    const int* __restrict__ cnt, const int* __restrict__ rows,
    const int* __restrict__ rowtab, const int* __restrict__ coltab) {
  const int e  = blockIdx.z;
  const int nrows = cnt[e];
  const int m0 = blockIdx.y * BM;
  if (m0 >= nrows) return;
  const int n0 = blockIdx.x * BN;
  const float* Bmat = We + (size_t)e * D_ * H_;
  const int* rl = rows + e * B_;

  __shared__ float As[2][BM][BK + 4];   // [2][64][20] f32 = 10240 B
  __shared__ float Bs[2][BK][BN + 8];   // [2][16][72] f32 =  9216 B

  const int tid = threadIdx.x;
  const int arow  = tid >> 2;               // [0,64)
  const int acol4 = (tid & 3) * 4;          // {0,4,8,12}
  const int brow  = tid >> 4;               // [0,16)
  const int bcol4 = (tid & 15) * 4;         // {0..60}

  const int gidx = m0 + arow;
  const int grow = rl[(gidx < nrows) ? gidx : (nrows - 1)];
  const float* aptr = X + (size_t)grow * D_;
  const float* bptr = Bmat + (size_t)brow * H_ + n0 + bcol4;

  const int lane = tid & 63;
  const int wave = tid >> 6;       // rows wave*16 .. +15
  const int lr = lane & 15;
  const int lq = lane >> 4;

  v4d acc[4];
#pragma unroll
  for (int c = 0; c < 4; ++c) acc[c] = (v4d){0.0, 0.0, 0.0, 0.0};

  // prologue: stage tile 0 into buf 0
  float4 av = *(const float4*)(aptr + acol4);
  float4 bv = *(const float4*)(bptr);
  *(float4*)&As[0][arow][acol4] = av;
  *(float4*)&Bs[0][brow][bcol4] = bv;

#define COMPUTE_TILE(BUF)                                                    \
  _Pragma("unroll")                                                          \
  for (int k4 = 0; k4 < BK; k4 += 4) {                                       \
    double a = (double)As[BUF][wave * 16 + lr][k4 + lq];                     \
    _Pragma("unroll")                                                        \
    for (int c = 0; c < 4; ++c) {                                            \
      double bb = (double)Bs[BUF][k4 + lq][c * 16 + lr];                     \
      acc[c] = __builtin_amdgcn_mfma_f64_16x16x4f64(a, bb, acc[c], 0, 0, 0); \
    }                                                                        \
  }

  for (int k0 = 0; k0 < D_; k0 += 2 * BK) {
    // ---- phase 0: compute buf0 (tile k0), prefetch k0+BK, write buf1 ----
    __syncthreads();                       // buf0 writes visible; buf1 free
    av = *(const float4*)(aptr + (k0 + BK) + acol4);
    bv = *(const float4*)(bptr + (size_t)(k0 + BK) * H_);
    COMPUTE_TILE(0)
    *(float4*)&As[1][arow][acol4] = av;
    *(float4*)&Bs[1][brow][bcol4] = bv;
    // ---- phase 1: compute buf1 (tile k0+BK), prefetch k0+2BK, write buf0 ----
    __syncthreads();                       // buf1 writes visible; buf0 free
    const bool more = (k0 + 2 * BK) < D_;
    if (more) {
      av = *(const float4*)(aptr + (k0 + 2 * BK) + acol4);
      bv = *(const float4*)(bptr + (size_t)(k0 + 2 * BK) * H_);
    }
    COMPUTE_TILE(1)
    if (more) {
      *(float4*)&As[0][arow][acol4] = av;
      *(float4*)&Bs[0][brow][bcol4] = bv;
    }
  }
#undef COMPUTE_TILE

  // epilogue via probed D layout
  int drow[4], dcol[4];
#pragma unroll
  for (int g = 0; g < 4; ++g) {
    drow[g] = rowtab[lane * 4 + g];
    dcol[g] = coltab[lane * 4 + g];
  }
#pragma unroll
  for (int c = 0; c < 4; ++c) {
#pragma unroll
    for (int g = 0; g < 4; ++g) {
      const int rix = m0 + wave * 16 + drow[g];
      if (rix < nrows) {
        const int mrow = rl[rix];
        const int col = n0 + c * 16 + dcol[g];
        out_all[((size_t)mrow * E_ + e) * H_ + col] =
            (float)(acc[c][g] + (double)be[(size_t)e * H_ + col]);
      }
    }
  }
}

// ---- 3. energy: bit-replica of numpy f32 logsumexp (verified R11) ----
__global__ __launch_bounds__(256) void energy_kernel(
    const float* __restrict__ out_all, const int* __restrict__ idx,
    float* __restrict__ energy) {
  const int b = blockIdx.x, j = blockIdx.y, t = threadIdx.x;
  const int e = idx[b * K_ + j];
  if (e == EXP_ID_) {
    if (t == 0) energy[b * K_ + j] = 1.0f + (float)log(2048.0);
    return;
  }
  const float* rep = out_all + ((size_t)b * E_ + EXP_ID_) * H_;
  const float* ok  = out_all + ((size_t)b * E_ + e) * H_;

  __shared__ float cs[H_];
  __shared__ float red[256];
  __shared__ float chain[128];

  float mx = -2.0f;
  for (int h = t; h < H_; h += 256) {
    float r = rep[h], o = ok[h];
    float num = r * o;
    float den = fabsf(r) * fabsf(o) + 1e-8f;
    float c = num / den;
    cs[h] = c;
    mx = fmaxf(mx, c);
  }
  red[t] = mx;
  __syncthreads();
  for (int off = 128; off > 0; off >>= 1) {
    if (t < off) red[t] = fmaxf(red[t], red[t + off]);
    __syncthreads();
  }
  const float m = red[0];
  __syncthreads();

  if (t < 128) {
    const int blk = t >> 3, jj = t & 7;
    const float* base = cs + blk * 128;
    float d0 = base[jj] - m;
    float r = (float)exp((double)d0);
#pragma unroll
    for (int q = 1; q < 16; ++q) {
      float dq = base[q * 8 + jj] - m;
      float term = (float)exp((double)dq);
      r = r + term;
    }
    chain[t] = r;
  }
  __syncthreads();

  if (t == 0) {
    float Bsum[16];
#pragma unroll
    for (int blk = 0; blk < 16; ++blk) {
      const float* c8 = chain + blk * 8;
      float s01 = c8[0] + c8[1];
      float s23 = c8[2] + c8[3];
      float s45 = c8[4] + c8[5];
      float s67 = c8[6] + c8[7];
      Bsum[blk] = (s01 + s23) + (s45 + s67);
    }
    float C[8], D[4], Ee[2];
#pragma unroll
    for (int i = 0; i < 8; ++i) C[i] = Bsum[2 * i] + Bsum[2 * i + 1];
#pragma unroll
    for (int i = 0; i < 4; ++i) D[i] = C[2 * i] + C[2 * i + 1];
#pragma unroll
    for (int i = 0; i < 2; ++i) Ee[i] = D[2 * i] + D[2 * i + 1];
    float S = Ee[0] + Ee[1];
    energy[b * K_ + j] = m + (float)log((double)S);
  }
}

// ---- 4. select: stable rank on f32 E bits (exact ties -> lower j), keep 6 ----
__global__ __launch_bounds__(256) void final_kernel(
    const float* __restrict__ out_all, const int* __restrict__ idx,
    const float* __restrict__ vals, const float* __restrict__ energy,
    float* __restrict__ out) {
  const int b = blockIdx.x;
  const int h = blockIdx.y * 256 + threadIdx.x;
  float En[K_];
#pragma unroll
  for (int j = 0; j < K_; ++j) En[j] = energy[b * K_ + j];
  double s = 0.0;
#pragma unroll
  for (int j = 0; j < K_; ++j) {
    int pos = 0;
#pragma unroll
    for (int j2 = 0; j2 < K_; ++j2)
      pos += (En[j2] < En[j]) || (En[j2] == En[j] && j2 < j);
    if (pos < KEEP_) {
      int e = idx[b * K_ + j];
      s += (double)vals[b * K_ + j] *
           (double)out_all[((size_t)b * E_ + e) * H_ + h];
    }
  }
  out[(size_t)b * H_ + h] = (float)s;
}

// ---------------- launch ----------------
extern "C" void kernel_launch(void* const* d_in, const int* in_sizes, int n_in,
                              void* d_out, int out_size, void* d_ws, size_t ws_size,
                              hipStream_t stream) {
  const float* x  = (const float*)d_in[0];
  const float* Wg = (const float*)d_in[1];
  const float* bg = (const float*)d_in[2];
  const float* We = (const float*)d_in[3];
  const float* be = (const float*)d_in[4];
  float* out = (float*)d_out;

  char* ws = (char*)d_ws;
  float* out_all = (float*)(ws + WS_OUTALL);
  int*   idx     = (int*)(ws + WS_IDX);
  float* vals    = (float*)(ws + WS_VALS);
  float* energy  = (float*)(ws + WS_ENERGY);
  int*   cnt     = (int*)(ws + WS_CNT);
  int*   rows    = (int*)(ws + WS_ROWS);
  int*   rowtab  = (int*)(ws + WS_ROWTAB);
  int*   coltab  = (int*)(ws + WS_COLTAB);
  int*   okflg   = (int*)(ws + WS_OKFLG);

  init_cnt_kernel<<<dim3(1), dim3(64), 0, stream>>>(cnt, okflg);

  mfma_probe_kernel<<<dim3(1), dim3(64), 0, stream>>>(rowtab, coltab, okflg);

  gate_kernel<<<dim3(B_), dim3(64), 0, stream>>>(x, Wg, bg, idx, vals, cnt, rows);

  gemm_expert_kernel<<<dim3(H_ / BN, B_ / BM, E_), dim3(256), 0, stream>>>(
      x, We, be, out_all, cnt, rows, rowtab, coltab);

  energy_kernel<<<dim3(B_, K_), dim3(256), 0, stream>>>(out_all, idx, energy);

  final_kernel<<<dim3(B_, H_ / 256), dim3(256), 0, stream>>>(
      out_all, idx, vals, energy, out);
}